// Round 3
// baseline (285.300 us; speedup 1.0000x reference)
//
#include <hip/hip_runtime.h>
#include <math.h>

#define EPSF 1e-20f
#define Bv 4
#define Cv 32
#define Ov 32
#define Hv 256
#define Wv 256
#define HOv 128
#define WOv 128
#define NPIX (HOv * WOv)          // 16384
#define HALF_OUT (Bv * Ov * NPIX) // 2,097,152

__device__ __forceinline__ float softplus_f(float x) {
    return fmaxf(x, 0.0f) + log1pf(__expf(-fabsf(x)));
}
__device__ __forceinline__ float frcp(float x) {
    return __builtin_amdgcn_rcpf(x);
}

// ws layout (floats):
//  [0..31]    wp (softplus)
//  [32..319]  sw (c*9+k)
//  [320..1343] cw (o*32+c)
//  [1344] 1/(sum_sw+EPS)   [1345] 1/(sum_cw+EPS)
//  [2048 ...] float2 buf[(b*32+c)*16384 + pix] = {cgx_sp*gx_sp, cgx_sp}  (16.8 MB)
#define WS_BUF_OFF 2048
#define WS_NEEDED (WS_BUF_OFF * 4 + (size_t)Bv * Cv * NPIX * 8)

__global__ void prep_kernel(const float* __restrict__ wp_raw,
                            const float* __restrict__ sw_raw,
                            const float* __restrict__ cw_raw,
                            float* __restrict__ ws) {
    __shared__ float red_sw[256];
    __shared__ float red_cw[256];
    const int t = threadIdx.x;
    float acc_sw = 0.f, acc_cw = 0.f;
    if (t < 32) ws[t] = softplus_f(wp_raw[t]);
    for (int i = t; i < 288; i += 256) {
        float v = softplus_f(sw_raw[i]);
        ws[32 + i] = v;
        acc_sw += v;
    }
    for (int i = t; i < 1024; i += 256) {
        float v = softplus_f(cw_raw[i]);
        ws[320 + i] = v;
        acc_cw += v;
    }
    red_sw[t] = acc_sw;
    red_cw[t] = acc_cw;
    __syncthreads();
    for (int st = 128; st > 0; st >>= 1) {
        if (t < st) { red_sw[t] += red_sw[t + st]; red_cw[t] += red_cw[t + st]; }
        __syncthreads();
    }
    if (t == 0) {
        ws[1344] = 1.0f / (red_sw[0] + EPSF);
        ws[1345] = 1.0f / (red_cw[0] + EPSF);
    }
}

// ================= K1: stage A (pointwise) + spatial 9-tap stage ==========
// tile: 8 output rows x 32 output cols per 256-thread block
// input tile: 17 rows x 65 cols, stored even/odd column-deinterleaved in LDS
#define TH1 8
#define TW1 32
#define IH1 17
#define IW1 65
#define NT1 (IH1 * IW1)   // 1105
#define NSLOT 5           // ceil(1105/256)
#define ESTRIDE 34        // even/odd sub-array row stride
#define HALFT (IH1 * ESTRIDE)  // 578: offset of odd-column sub-array

__global__ __launch_bounds__(256)
void k1_spatial(const float* __restrict__ d,  const float* __restrict__ cd,
                const float* __restrict__ s,  const float* __restrict__ gx,
                const float* __restrict__ cgx, const float* __restrict__ sprod,
                const float* __restrict__ ws, float2* __restrict__ buf) {
    __shared__ float lgx[2 * HALFT];
    __shared__ float lcg[2 * HALFT];

    const int t    = threadIdx.x;
    const int wo_l = t & 31;
    const int ho_l = t >> 5;              // 0..7
    const int wo0  = blockIdx.x * TW1;
    const int ho0  = blockIdx.y * TH1;
    const int z    = blockIdx.z;          // b*32 + c
    const int c    = z & 31;

    const int ho   = ho0 + ho_l;
    const int wo   = wo0 + wo_l;

    const float wpc = ws[c];              // uniform (scalar)
    const float inv_wp1 = frcp(wpc + 1.0f);
    const float inv_sumsw = ws[1344];
    const float* sw_c = ws + 32 + c * 9;

    const int ibase  = z * (Hv * Wv);
    const int h_base = 2 * ho0 - 1;
    const int w_base = 2 * wo0 - 1;

    // ---- phase 1: issue ALL stage-A loads (25) + ALL sprod loads (9) ----
    // clamped-safe addresses so loads are unconditional -> max MLP
    int   lidx[NSLOT];
    bool  val[NSLOT], mL[NSLOT], mR[NSLOT];
    float dv[NSLOT], cdv[NSLOT], sv[NSLOT], gxv[NSLOT], cgv[NSLOT];
#pragma unroll
    for (int j = 0; j < NSLOT; ++j) {
        const int idx = t + 256 * j;
        const int r   = idx / IW1;           // const divisor -> magic mul
        const int cc  = idx - r * IW1;
        const int h   = h_base + r;
        const int w   = w_base + cc;
        const bool v  = (idx < NT1) && ((unsigned)h < (unsigned)Hv)
                                    && ((unsigned)w < (unsigned)Wv);
        lidx[j] = idx;
        val[j]  = v;
        mL[j]   = (w != Wv - 1);   // pad_r zeros last col
        mR[j]   = (w != 0);        // pad_l zeros first col
        const int p = v ? (ibase + h * Wv + w) : ibase;
        dv[j]  = d[p];
        cdv[j] = cd[p];
        sv[j]  = s[p];
        gxv[j] = gx[p];
        cgv[j] = cgx[p];
    }
    const int spb = (z * 9 * HOv + ho) * WOv + wo;
    float spv[9];
#pragma unroll
    for (int k = 0; k < 9; ++k) spv[k] = sprod[spb + k * NPIX];

    // ---- phase 2: stage-A compute + LDS writes (even/odd deinterleave) ----
#pragma unroll
    for (int j = 0; j < NSLOT; ++j) {
        const bool v = val[j];
        const float dV  = v ? dv[j]  : 0.f;
        const float cdV = v ? cdv[j] : 0.f;
        const float sV  = v ? sv[j]  : 0.f;
        const float gV  = v ? gxv[j] : 0.f;
        const float cV  = v ? cgv[j] : 0.f;
        const float dL  = mL[j] ? dV  : 0.f;
        const float cdL = mL[j] ? cdV : 0.f;
        const float sL  = mL[j] ? sV  : 0.f;
        const float dR  = mR[j] ? dV  : 0.f;
        const float cdR = mR[j] ? cdV : 0.f;
        const float sR  = mR[j] ? sV  : 0.f;
        const float cgx_ds = sV * sL * sR * cdL * cdR;
        const float height = (cdL * dV * (mL[j] ? 1.f : 0.f) + cdR * dR) * 0.f +
                             (cdL * dL + cdR * dR) * frcp(cdL + cdR + EPSF);
        const float gx_ds  = (dR - dL) * 0.5f * frcp(height + EPSF);
        const float a = wpc * cV;
        const float gxn = (a * gV + cgx_ds * gx_ds) * frcp(a + cgx_ds + EPSF);
        const float cgn = (a + cgx_ds) * inv_wp1;
        if (lidx[j] < NT1) {
            const int r  = lidx[j] / IW1;
            const int cc = lidx[j] - r * IW1;
            const int laddr = (cc & 1) * HALFT + r * ESTRIDE + (cc >> 1);
            lgx[laddr] = v ? gxn : 0.f;
            lcg[laddr] = v ? cgn : 0.f;
        }
    }
    __syncthreads();

    // ---- phase 3: spatial 9-tap combine (sprod already in regs) ----
    float nom = 0.f, den = 0.f;
#pragma unroll
    for (int k = 0; k < 9; ++k) {
        const int ki = k / 3;
        const int kj = k - ki * 3;
        const int ir = 2 * ho_l + ki;
        const int laddr = (kj == 1) ? (HALFT + ir * ESTRIDE + wo_l)
                                    : (ir * ESTRIDE + wo_l + (kj >> 1));
        const float gxr = lgx[laddr];
        const float cgr = lcg[laddr];
        const float cp  = cgr * spv[k] * sw_c[k];
        den += cp;
        nom = fmaf(cp, gxr, nom);
    }
    const float gx_sp  = nom * frcp(den + EPSF);
    const float cgx_sp = den * inv_sumsw;
    buf[z * NPIX + ho * WOv + wo] = make_float2(cgx_sp * gx_sp, cgx_sp);
}

// ================= K2: 32->32 channel mix (o split in 2 groups) ===========
__global__ __launch_bounds__(256)
void k2_channel(const float2* __restrict__ buf, const float* __restrict__ ws,
                const float* __restrict__ bias, float* __restrict__ out) {
    const int pg  = blockIdx.x * 256 + threadIdx.x;  // 0..65535
    const int b   = pg >> 14;
    const int pp  = pg & (NPIX - 1);
    const int grp = blockIdx.y;                      // 0..1
    const float* cw_t = ws + 320;
    const float inv_sumcw = ws[1345];

    float nom2[16], den2[16];
#pragma unroll
    for (int i = 0; i < 16; ++i) { nom2[i] = 0.f; den2[i] = 0.f; }

    const int cbase = b * Cv * NPIX + pp;
#pragma unroll
    for (int cc = 0; cc < Cv; ++cc) {
        const float2 v = buf[cbase + cc * NPIX];
#pragma unroll
        for (int oi = 0; oi < 16; ++oi) {
            const float w_ = cw_t[(grp * 16 + oi) * Cv + cc];  // uniform
            nom2[oi] = fmaf(v.x, w_, nom2[oi]);
            den2[oi] = fmaf(v.y, w_, den2[oi]);
        }
    }
#pragma unroll
    for (int oi = 0; oi < 16; ++oi) {
        const int o = grp * 16 + oi;
        const int p = (b * Ov + o) * NPIX + pp;
        const float dn = den2[oi];
        const float g  = nom2[oi] * frcp(dn + EPSF) + bias[o];
        out[p]            = g * 2.0f;
        out[HALF_OUT + p] = dn * inv_sumcw * 0.25f;
    }
}

// ================= fallback: fully fused (round-1) kernel =================
#define TH 4
#define TW 32
#define IH 9
#define IW 65
#define IWP 66
#define NTILE (IH * IW)

__global__ __launch_bounds__(128)
void main_kernel(const float* __restrict__ d,  const float* __restrict__ cd,
                 const float* __restrict__ s,  const float* __restrict__ gx,
                 const float* __restrict__ cgx, const float* __restrict__ sprod,
                 const float* __restrict__ bias, const float* __restrict__ ws,
                 float* __restrict__ out) {
    __shared__ float lgx[IH][IWP];
    __shared__ float lcgx[IH][IWP];
    const int t    = threadIdx.x;
    const int wo_l = t & 31;
    const int ho_l = t >> 5;
    const int wo0  = blockIdx.x * TW;
    const int ho0  = blockIdx.y * TH;
    const int b    = blockIdx.z;
    const int ho   = ho0 + ho_l;
    const int wo   = wo0 + wo_l;
    const float* sw_t = ws + 32;
    const float* cw_t = ws + 320;
    const float inv_sumsw = ws[1344];
    const float inv_sumcw = ws[1345];
    float nom2[Ov], den2[Ov];
#pragma unroll
    for (int o = 0; o < Ov; ++o) { nom2[o] = 0.f; den2[o] = 0.f; }
    const int h_base = 2 * ho0 - 1;
    const int w_base = 2 * wo0 - 1;
    for (int c = 0; c < Cv; ++c) {
        const float wpc = ws[c];
        const float inv_wp1 = frcp(wpc + 1.0f);
        const int ibase = (b * Cv + c) * (Hv * Wv);
        for (int idx = t; idx < NTILE; idx += 128) {
            const int r  = idx / IW;
            const int cc = idx - r * IW;
            const int h  = h_base + r;
            const int w  = w_base + cc;
            float gxn = 0.f, cgxn = 0.f;
            if ((unsigned)h < (unsigned)Hv && (unsigned)w < (unsigned)Wv) {
                const int p = ibase + h * Wv + w;
                const float dv = d[p], cdv = cd[p], sv = s[p];
                const float gxv = gx[p], cgxv = cgx[p];
                const bool mLb = (w != Wv - 1);
                const bool mRb = (w != 0);
                const float dL = mLb ? dv : 0.f, cdL = mLb ? cdv : 0.f, sL = mLb ? sv : 0.f;
                const float dR = mRb ? dv : 0.f, cdR = mRb ? cdv : 0.f, sR = mRb ? sv : 0.f;
                const float cgx_ds = sv * sL * sR * cdL * cdR;
                const float height = (cdL * dL + cdR * dR) * frcp(cdL + cdR + EPSF);
                const float gx_ds  = (dR - dL) * 0.5f * frcp(height + EPSF);
                const float a = wpc * cgxv;
                gxn  = (a * gxv + cgx_ds * gx_ds) * frcp(a + cgx_ds + EPSF);
                cgxn = (a + cgx_ds) * inv_wp1;
            }
            lgx[r][cc]  = gxn;
            lcgx[r][cc] = cgxn;
        }
        __syncthreads();
        const int spb = ((b * Cv + c) * 9 * HOv + ho) * WOv + wo;
        float nom = 0.f, den = 0.f;
#pragma unroll
        for (int k = 0; k < 9; ++k) {
            const int ki = k / 3;
            const int kj = k - ki * 3;
            const float gxr  = lgx[2 * ho_l + ki][2 * wo_l + kj];
            const float cgxr = lcgx[2 * ho_l + ki][2 * wo_l + kj];
            const float spv  = sprod[spb + k * NPIX];
            const float cp   = cgxr * spv * sw_t[c * 9 + k];
            den += cp;
            nom = fmaf(cp, gxr, nom);
        }
        const float gx_sp  = nom * frcp(den + EPSF);
        const float cgx_sp = den * inv_sumsw;
        const float t1 = cgx_sp * gx_sp;
#pragma unroll
        for (int o = 0; o < Ov; ++o) {
            const float w_ = cw_t[o * Cv + c];
            nom2[o] = fmaf(t1, w_, nom2[o]);
            den2[o] = fmaf(cgx_sp, w_, den2[o]);
        }
        __syncthreads();
    }
#pragma unroll
    for (int o = 0; o < Ov; ++o) {
        const int p = ((b * Ov + o) * HOv + ho) * WOv + wo;
        const float dn = den2[o];
        const float g  = nom2[o] * frcp(dn + EPSF) + bias[o];
        out[p]            = g * 2.0f;
        out[HALF_OUT + p] = dn * inv_sumcw * 0.25f;
    }
}

extern "C" void kernel_launch(void* const* d_in, const int* in_sizes, int n_in,
                              void* d_out, int out_size, void* d_ws, size_t ws_size,
                              hipStream_t stream) {
    const float* d_ptr    = (const float*)d_in[0];
    const float* cd_ptr   = (const float*)d_in[1];
    const float* s_ptr    = (const float*)d_in[2];
    // d_in[3] = cs : unused by the reference
    const float* gx_ptr   = (const float*)d_in[4];
    const float* cgx_ptr  = (const float*)d_in[5];
    const float* sp_ptr   = (const float*)d_in[6];
    const float* wp_ptr   = (const float*)d_in[7];
    const float* sw_ptr   = (const float*)d_in[8];
    const float* cw_ptr   = (const float*)d_in[9];
    const float* bias_ptr = (const float*)d_in[10];
    float* out = (float*)d_out;
    float* ws  = (float*)d_ws;

    prep_kernel<<<1, 256, 0, stream>>>(wp_ptr, sw_ptr, cw_ptr, ws);

    if (ws_size >= WS_NEEDED) {
        float2* buf = (float2*)(ws + WS_BUF_OFF);
        dim3 g1(WOv / TW1, HOv / TH1, Bv * Cv);   // 4 x 16 x 128 = 8192 blocks
        k1_spatial<<<g1, 256, 0, stream>>>(d_ptr, cd_ptr, s_ptr, gx_ptr, cgx_ptr,
                                           sp_ptr, ws, buf);
        dim3 g2((Bv * NPIX) / 256, 2, 1);         // 256 x 2 blocks
        k2_channel<<<g2, 256, 0, stream>>>(buf, ws, bias_ptr, out);
    } else {
        dim3 grid(WOv / TW, HOv / TH, Bv);
        main_kernel<<<grid, 128, 0, stream>>>(d_ptr, cd_ptr, s_ptr, gx_ptr, cgx_ptr,
                                              sp_ptr, bias_ptr, ws, out);
    }
}

// Round 4
// 282.012 us; speedup vs baseline: 1.0117x; 1.0117x over previous
//
#include <hip/hip_runtime.h>
#include <math.h>

#define EPSF 1e-20f
#define Bv 4
#define Cv 32
#define Ov 32
#define Hv 256
#define Wv 256
#define HOv 128
#define WOv 128
#define NPIX (HOv * WOv)          // 16384
#define HALF_OUT (Bv * Ov * NPIX) // 2,097,152

__device__ __forceinline__ float softplus_f(float x) {
    return fmaxf(x, 0.0f) + log1pf(__expf(-fabsf(x)));
}
__device__ __forceinline__ float frcp(float x) {
    return __builtin_amdgcn_rcpf(x);
}

// ws layout (floats):
//  [0..31]     wp (softplus)
//  [32..319]   sw (c*9+k)
//  [320..1343] cw (o*32+c)
//  [1344] 1/(sum_sw+EPS)   [1345] 1/(sum_cw+EPS)
//  [2048 ...]  float2 buf[(b*32+c)*16384 + pix] = {cgx_sp*gx_sp, cgx_sp} (16.8MB)
#define WS_BUF_OFF 2048
#define WS_NEEDED (WS_BUF_OFF * 4 + (size_t)Bv * Cv * NPIX * 8)

__global__ void prep_kernel(const float* __restrict__ wp_raw,
                            const float* __restrict__ sw_raw,
                            const float* __restrict__ cw_raw,
                            float* __restrict__ ws) {
    __shared__ float red_sw[256];
    __shared__ float red_cw[256];
    const int t = threadIdx.x;
    float acc_sw = 0.f, acc_cw = 0.f;
    if (t < 32) ws[t] = softplus_f(wp_raw[t]);
    for (int i = t; i < 288; i += 256) {
        float v = softplus_f(sw_raw[i]);
        ws[32 + i] = v;
        acc_sw += v;
    }
    for (int i = t; i < 1024; i += 256) {
        float v = softplus_f(cw_raw[i]);
        ws[320 + i] = v;
        acc_cw += v;
    }
    red_sw[t] = acc_sw;
    red_cw[t] = acc_cw;
    __syncthreads();
    for (int st = 128; st > 0; st >>= 1) {
        if (t < st) { red_sw[t] += red_sw[t + st]; red_cw[t] += red_cw[t + st]; }
        __syncthreads();
    }
    if (t == 0) {
        ws[1344] = 1.0f / (red_sw[0] + EPSF);
        ws[1345] = 1.0f / (red_cw[0] + EPSF);
    }
}

// ================= K1: stage A + spatial stage, full-width tiles ==========
// Block: 256 threads = 4 waves. Tile: 4 output rows x 128 cols (full width).
// Input: 9 rows x 256 cols. Wave q stages rows {q, q+4, q+8}; each lane loads
// one float4 (row = 64 lanes * 4). Phase 3: thread (l,q) computes pixels
// (ho0+q, 2l) and (ho0+q, 2l+1).
#define TH1 4
#define IR 9
#define LS 260            // LDS row stride in floats (256 + 4 pad)

__global__ __launch_bounds__(256)
void k1_spatial(const float* __restrict__ d,  const float* __restrict__ cd,
                const float* __restrict__ s,  const float* __restrict__ gx,
                const float* __restrict__ cgx, const float* __restrict__ sprod,
                const float* __restrict__ ws, float2* __restrict__ buf) {
    __shared__ float lgx[IR * LS];
    __shared__ float lcg[IR * LS];

    const int t  = threadIdx.x;
    const int l  = t & 63;            // lane
    const int q  = t >> 6;            // wave id 0..3
    const int tile = blockIdx.x;      // 0..31
    const int z    = blockIdx.y;      // b*32 + c
    const int c    = z & 31;
    const int ho0  = tile * TH1;
    const int ho   = ho0 + q;

    const float wpc = ws[c];                  // wave-uniform -> scalar
    const float inv_wp1 = frcp(wpc + 1.0f);
    const float inv_sumsw = ws[1344];
    const float* sw_c = ws + 32 + c * 9;

    const int ibase = z * (Hv * Wv);
    const int h_top = 2 * ho0 - 1;

    // ---- sprod loads first (independent of everything; 9 x float2) ----
    const int sp0 = (z * 9 * HOv + ho) * WOv + 2 * l;
    float2 sp[9];
#pragma unroll
    for (int k = 0; k < 9; ++k)
        sp[k] = *(const float2*)(sprod + sp0 + k * NPIX);

    // ---- staging: unconditional float4 row loads + stage-A compute ----
#pragma unroll
    for (int p = 0; p < 3; ++p) {
        const int ri = p * 4 + q;
        if (ri < IR) {                         // wave-uniform (false only p=2,q>0)
            const int h  = h_top + ri;
            const int hs = (h < 0) ? 0 : h;    // clamped-safe, unconditional loads
            const int gb = ibase + hs * Wv + 4 * l;
            const float4 dv4 = *(const float4*)(d   + gb);
            const float4 cd4 = *(const float4*)(cd  + gb);
            const float4 sv4 = *(const float4*)(s   + gb);
            const float4 gx4 = *(const float4*)(gx  + gb);
            const float4 cg4 = *(const float4*)(cgx + gb);
            float go[4], co[4];
            const float dvA[4]  = {dv4.x, dv4.y, dv4.z, dv4.w};
            const float cdA[4]  = {cd4.x, cd4.y, cd4.z, cd4.w};
            const float svA[4]  = {sv4.x, sv4.y, sv4.z, sv4.w};
            const float gxA[4]  = {gx4.x, gx4.y, gx4.z, gx4.w};
            const float cgA[4]  = {cg4.x, cg4.y, cg4.z, cg4.w};
#pragma unroll
            for (int e = 0; e < 4; ++e) {
                const int w = 4 * l + e;
                const bool mL = (w != Wv - 1);     // pad_r zeros last col
                const bool mR = (w != 0);          // pad_l zeros first col
                const float dV = dvA[e], cdV = cdA[e], sV = svA[e];
                const float dL  = mL ? dV  : 0.f;
                const float cdL = mL ? cdV : 0.f;
                const float sL  = mL ? sV  : 0.f;
                const float dR  = mR ? dV  : 0.f;
                const float cdR = mR ? cdV : 0.f;
                const float sR  = mR ? sV  : 0.f;
                const float cgx_ds = sV * sL * sR * cdL * cdR;
                const float height = (cdL * dL + cdR * dR) * frcp(cdL + cdR + EPSF);
                const float gx_ds  = (dR - dL) * 0.5f * frcp(height + EPSF);
                const float a = wpc * cgA[e];
                float gn = (a * gxA[e] + cgx_ds * gx_ds) * frcp(a + cgx_ds + EPSF);
                float cn = (a + cgx_ds) * inv_wp1;
                go[e] = (h < 0) ? 0.f : gn;        // cndmask, no branch
                co[e] = (h < 0) ? 0.f : cn;
            }
            float4 g4 = {go[0], go[1], go[2], go[3]};
            float4 c4 = {co[0], co[1], co[2], co[3]};
            *(float4*)&lgx[ri * LS + 4 * l] = g4;   // dense, 16B-aligned
            *(float4*)&lcg[ri * LS + 4 * l] = c4;
        }
    }
    __syncthreads();

    // ---- phase 3: two pixels per thread, aligned b128 LDS reads ----
    float nom0 = 0.f, den0 = 0.f, nom1 = 0.f, den1 = 0.f;
#pragma unroll
    for (int ki = 0; ki < 3; ++ki) {
        const int ri = 2 * q + ki;                 // 0..8
        const float4 g4 = *(const float4*)&lgx[ri * LS + 4 * l];
        const float4 c4 = *(const float4*)&lcg[ri * LS + 4 * l];
        const int ei = ri * LS + (l ? (4 * l - 1) : 0);
        float ge = lgx[ei];  ge = l ? ge : 0.f;    // w = -1 tap is zero
        float ce = lcg[ei];  ce = l ? ce : 0.f;
        const float sw0 = sw_c[3 * ki + 0];
        const float sw1 = sw_c[3 * ki + 1];
        const float sw2 = sw_c[3 * ki + 2];
        float cp;
        // pixel wo0 = 2l : taps w = 4l-1, 4l, 4l+1
        cp = ce   * sp[3 * ki + 0].x * sw0; den0 += cp; nom0 = fmaf(cp, ge,   nom0);
        cp = c4.x * sp[3 * ki + 1].x * sw1; den0 += cp; nom0 = fmaf(cp, g4.x, nom0);
        cp = c4.y * sp[3 * ki + 2].x * sw2; den0 += cp; nom0 = fmaf(cp, g4.y, nom0);
        // pixel wo1 = 2l+1 : taps w = 4l+1, 4l+2, 4l+3
        cp = c4.y * sp[3 * ki + 0].y * sw0; den1 += cp; nom1 = fmaf(cp, g4.y, nom1);
        cp = c4.z * sp[3 * ki + 1].y * sw1; den1 += cp; nom1 = fmaf(cp, g4.z, nom1);
        cp = c4.w * sp[3 * ki + 2].y * sw2; den1 += cp; nom1 = fmaf(cp, g4.w, nom1);
    }
    const float gx0 = nom0 * frcp(den0 + EPSF);
    const float cg0 = den0 * inv_sumsw;
    const float gx1 = nom1 * frcp(den1 + EPSF);
    const float cg1 = den1 * inv_sumsw;
    float4 ov = {cg0 * gx0, cg0, cg1 * gx1, cg1};
    *(float4*)(buf + (size_t)z * NPIX + ho * WOv + 2 * l) = ov;
}

// ================= K2: 32->32 channel mix (o split in 2 groups) ===========
__global__ __launch_bounds__(256)
void k2_channel(const float2* __restrict__ buf, const float* __restrict__ ws,
                const float* __restrict__ bias, float* __restrict__ out) {
    const int pg  = blockIdx.x * 256 + threadIdx.x;  // 0..65535
    const int b   = pg >> 14;
    const int pp  = pg & (NPIX - 1);
    const int grp = blockIdx.y;                      // 0..1
    const float* cw_t = ws + 320;
    const float inv_sumcw = ws[1345];

    float nom2[16], den2[16];
#pragma unroll
    for (int i = 0; i < 16; ++i) { nom2[i] = 0.f; den2[i] = 0.f; }

    const int cbase = b * Cv * NPIX + pp;
#pragma unroll
    for (int cc = 0; cc < Cv; ++cc) {
        const float2 v = buf[cbase + cc * NPIX];
#pragma unroll
        for (int oi = 0; oi < 16; ++oi) {
            const float w_ = cw_t[(grp * 16 + oi) * Cv + cc];  // uniform
            nom2[oi] = fmaf(v.x, w_, nom2[oi]);
            den2[oi] = fmaf(v.y, w_, den2[oi]);
        }
    }
#pragma unroll
    for (int oi = 0; oi < 16; ++oi) {
        const int o = grp * 16 + oi;
        const int p = (b * Ov + o) * NPIX + pp;
        const float dn = den2[oi];
        const float g  = nom2[oi] * frcp(dn + EPSF) + bias[o];
        out[p]            = g * 2.0f;
        out[HALF_OUT + p] = dn * inv_sumcw * 0.25f;
    }
}

// ================= fallback: fully fused (round-1) kernel =================
#define TH 4
#define TW 32
#define IH 9
#define IW 65
#define IWP 66
#define NTILE (IH * IW)

__global__ __launch_bounds__(128)
void main_kernel(const float* __restrict__ d,  const float* __restrict__ cd,
                 const float* __restrict__ s,  const float* __restrict__ gx,
                 const float* __restrict__ cgx, const float* __restrict__ sprod,
                 const float* __restrict__ bias, const float* __restrict__ ws,
                 float* __restrict__ out) {
    __shared__ float lgx[IH][IWP];
    __shared__ float lcgx[IH][IWP];
    const int t    = threadIdx.x;
    const int wo_l = t & 31;
    const int ho_l = t >> 5;
    const int wo0  = blockIdx.x * TW;
    const int ho0  = blockIdx.y * TH;
    const int b    = blockIdx.z;
    const int ho   = ho0 + ho_l;
    const int wo   = wo0 + wo_l;
    const float* sw_t = ws + 32;
    const float* cw_t = ws + 320;
    const float inv_sumsw = ws[1344];
    const float inv_sumcw = ws[1345];
    float nom2[Ov], den2[Ov];
#pragma unroll
    for (int o = 0; o < Ov; ++o) { nom2[o] = 0.f; den2[o] = 0.f; }
    const int h_base = 2 * ho0 - 1;
    const int w_base = 2 * wo0 - 1;
    for (int c = 0; c < Cv; ++c) {
        const float wpc = ws[c];
        const float inv_wp1 = frcp(wpc + 1.0f);
        const int ibase = (b * Cv + c) * (Hv * Wv);
        for (int idx = t; idx < NTILE; idx += 128) {
            const int r  = idx / IW;
            const int cc = idx - r * IW;
            const int h  = h_base + r;
            const int w  = w_base + cc;
            float gxn = 0.f, cgxn = 0.f;
            if ((unsigned)h < (unsigned)Hv && (unsigned)w < (unsigned)Wv) {
                const int p = ibase + h * Wv + w;
                const float dv = d[p], cdv = cd[p], sv = s[p];
                const float gxv = gx[p], cgxv = cgx[p];
                const bool mLb = (w != Wv - 1);
                const bool mRb = (w != 0);
                const float dL = mLb ? dv : 0.f, cdL = mLb ? cdv : 0.f, sL = mLb ? sv : 0.f;
                const float dR = mRb ? dv : 0.f, cdR = mRb ? cdv : 0.f, sR = mRb ? sv : 0.f;
                const float cgx_ds = sv * sL * sR * cdL * cdR;
                const float height = (cdL * dL + cdR * dR) * frcp(cdL + cdR + EPSF);
                const float gx_ds  = (dR - dL) * 0.5f * frcp(height + EPSF);
                const float a = wpc * cgxv;
                gxn  = (a * gxv + cgx_ds * gx_ds) * frcp(a + cgx_ds + EPSF);
                cgxn = (a + cgx_ds) * inv_wp1;
            }
            lgx[r][cc]  = gxn;
            lcgx[r][cc] = cgxn;
        }
        __syncthreads();
        const int spb = ((b * Cv + c) * 9 * HOv + ho) * WOv + wo;
        float nom = 0.f, den = 0.f;
#pragma unroll
        for (int k = 0; k < 9; ++k) {
            const int ki = k / 3;
            const int kj = k - ki * 3;
            const float gxr  = lgx[2 * ho_l + ki][2 * wo_l + kj];
            const float cgxr = lcgx[2 * ho_l + ki][2 * wo_l + kj];
            const float spv  = sprod[spb + k * NPIX];
            const float cp   = cgxr * spv * sw_t[c * 9 + k];
            den += cp;
            nom = fmaf(cp, gxr, nom);
        }
        const float gx_sp  = nom * frcp(den + EPSF);
        const float cgx_sp = den * inv_sumsw;
        const float t1 = cgx_sp * gx_sp;
#pragma unroll
        for (int o = 0; o < Ov; ++o) {
            const float w_ = cw_t[o * Cv + c];
            nom2[o] = fmaf(t1, w_, nom2[o]);
            den2[o] = fmaf(cgx_sp, w_, den2[o]);
        }
        __syncthreads();
    }
#pragma unroll
    for (int o = 0; o < Ov; ++o) {
        const int p = ((b * Ov + o) * HOv + ho) * WOv + wo;
        const float dn = den2[o];
        const float g  = nom2[o] * frcp(dn + EPSF) + bias[o];
        out[p]            = g * 2.0f;
        out[HALF_OUT + p] = dn * inv_sumcw * 0.25f;
    }
}

extern "C" void kernel_launch(void* const* d_in, const int* in_sizes, int n_in,
                              void* d_out, int out_size, void* d_ws, size_t ws_size,
                              hipStream_t stream) {
    const float* d_ptr    = (const float*)d_in[0];
    const float* cd_ptr   = (const float*)d_in[1];
    const float* s_ptr    = (const float*)d_in[2];
    // d_in[3] = cs : unused by the reference
    const float* gx_ptr   = (const float*)d_in[4];
    const float* cgx_ptr  = (const float*)d_in[5];
    const float* sp_ptr   = (const float*)d_in[6];
    const float* wp_ptr   = (const float*)d_in[7];
    const float* sw_ptr   = (const float*)d_in[8];
    const float* cw_ptr   = (const float*)d_in[9];
    const float* bias_ptr = (const float*)d_in[10];
    float* out = (float*)d_out;
    float* ws  = (float*)d_ws;

    prep_kernel<<<1, 256, 0, stream>>>(wp_ptr, sw_ptr, cw_ptr, ws);

    if (ws_size >= WS_NEEDED) {
        float2* buf = (float2*)(ws + WS_BUF_OFF);
        dim3 g1(HOv / TH1, Bv * Cv, 1);          // 32 x 128 = 4096 blocks
        k1_spatial<<<g1, 256, 0, stream>>>(d_ptr, cd_ptr, s_ptr, gx_ptr, cgx_ptr,
                                           sp_ptr, ws, buf);
        dim3 g2((Bv * NPIX) / 256, 2, 1);        // 256 x 2 blocks
        k2_channel<<<g2, 256, 0, stream>>>(buf, ws, bias_ptr, out);
    } else {
        dim3 grid(WOv / TW, HOv / TH, Bv);
        main_kernel<<<grid, 128, 0, stream>>>(d_ptr, cd_ptr, s_ptr, gx_ptr, cgx_ptr,
                                              sp_ptr, bias_ptr, ws, out);
    }
}

// Round 5
// 280.613 us; speedup vs baseline: 1.0167x; 1.0050x over previous
//
#include <hip/hip_runtime.h>
#include <math.h>

#define EPSF 1e-20f
#define Bv 4
#define Cv 32
#define Ov 32
#define Hv 256
#define Wv 256
#define HOv 128
#define WOv 128
#define NPIX (HOv * WOv)          // 16384
#define HALF_OUT (Bv * Ov * NPIX) // 2,097,152

__device__ __forceinline__ float softplus_f(float x) {
    return fmaxf(x, 0.0f) + log1pf(__expf(-fabsf(x)));
}
__device__ __forceinline__ float frcp(float x) {
    return __builtin_amdgcn_rcpf(x);
}

// ws layout (floats):
//  [0..31]     wp (softplus)
//  [32..319]   sw (c*9+k)
//  [320..1343] cw (o*32+c)
//  [1344] 1/(sum_sw+EPS)   [1345] 1/(sum_cw+EPS)
//  [2048 ...]  float2 buf[(b*32+c)*16384 + pix] = {cgx_sp*gx_sp, cgx_sp} (16.8MB)
#define WS_BUF_OFF 2048
#define WS_NEEDED (WS_BUF_OFF * 4 + (size_t)Bv * Cv * NPIX * 8)

__global__ void prep_kernel(const float* __restrict__ wp_raw,
                            const float* __restrict__ sw_raw,
                            const float* __restrict__ cw_raw,
                            float* __restrict__ ws) {
    __shared__ float red_sw[256];
    __shared__ float red_cw[256];
    const int t = threadIdx.x;
    float acc_sw = 0.f, acc_cw = 0.f;
    if (t < 32) ws[t] = softplus_f(wp_raw[t]);
    for (int i = t; i < 288; i += 256) {
        float v = softplus_f(sw_raw[i]);
        ws[32 + i] = v;
        acc_sw += v;
    }
    for (int i = t; i < 1024; i += 256) {
        float v = softplus_f(cw_raw[i]);
        ws[320 + i] = v;
        acc_cw += v;
    }
    red_sw[t] = acc_sw;
    red_cw[t] = acc_cw;
    __syncthreads();
    for (int st = 128; st > 0; st >>= 1) {
        if (t < st) { red_sw[t] += red_sw[t + st]; red_cw[t] += red_cw[t + st]; }
        __syncthreads();
    }
    if (t == 0) {
        ws[1344] = 1.0f / (red_sw[0] + EPSF);
        ws[1345] = 1.0f / (red_cw[0] + EPSF);
    }
}

// ================= K1: no-LDS, no-barrier, shuffle for left tap ==========
// One wave per output row slice: lane l computes pixels (ho, 2l) and (ho,
// 2l+1). It loads its own 3 input rows (h = 2ho-1 .. 2ho+1) as float4 per
// array (15 float4 loads, all independent) + 9 float2 sprod loads. Stage A
// is pointwise; the left tap (stage-A output at col 4l-1) comes from lane
// l-1 elem 3 via __shfl_up. Vertical re-reads hit L1/L2 (same/adjacent
// waves), not HBM. __launch_bounds__(256,2) lifts the VGPR cap to 256 so
// the compiler keeps all 24 loads in flight (rounds 3/4 got squeezed to
// 36-40 VGPR and serialized).
__global__ __launch_bounds__(256, 2)
void k1_spatial(const float* __restrict__ d,  const float* __restrict__ cd,
                const float* __restrict__ s,  const float* __restrict__ gx,
                const float* __restrict__ cgx, const float* __restrict__ sprod,
                const float* __restrict__ ws, float2* __restrict__ buf) {
    const int t  = threadIdx.x;
    const int l  = t & 63;            // lane
    const int q  = t >> 6;            // wave id 0..3
    const int ho = blockIdx.x * 4 + q;
    const int z  = blockIdx.y;        // b*32 + c
    const int c  = z & 31;

    const float wpc = ws[c];                  // wave-uniform -> scalar
    const float inv_wp1 = frcp(wpc + 1.0f);
    const float inv_sumsw = ws[1344];
    const float* sw_c = ws + 32 + c * 9;

    const int ibase = z * (Hv * Wv);
    const int h_top = 2 * ho - 1;
    const bool row0_ok = (h_top >= 0);        // only false for ho==0
    const int col = 4 * l;

    int gaddr[3];
    gaddr[0] = ibase + (row0_ok ? h_top : 0) * Wv + col;  // clamped-safe
    gaddr[1] = ibase + (h_top + 1) * Wv + col;
    gaddr[2] = ibase + (h_top + 2) * Wv + col;

    // ---- issue ALL loads up front (15 float4 + 9 float2, independent) ----
    float4 Dv[3], Cd[3], Sv[3], Gv[3], Cg[3];
#pragma unroll
    for (int r = 0; r < 3; ++r) {
        Dv[r] = *(const float4*)(d   + gaddr[r]);
        Cd[r] = *(const float4*)(cd  + gaddr[r]);
        Sv[r] = *(const float4*)(s   + gaddr[r]);
        Gv[r] = *(const float4*)(gx  + gaddr[r]);
        Cg[r] = *(const float4*)(cgx + gaddr[r]);
    }
    const int sp0 = (z * 9 * HOv + ho) * WOv + 2 * l;
    float2 sp[9];
#pragma unroll
    for (int k = 0; k < 9; ++k)
        sp[k] = *(const float2*)(sprod + sp0 + k * NPIX);

    // ---- per row: stage-A (pointwise) + shfl left tap + spatial taps ----
    float nom0 = 0.f, den0 = 0.f, nom1 = 0.f, den1 = 0.f;
#pragma unroll
    for (int r = 0; r < 3; ++r) {
        const bool vrow = (r > 0) || row0_ok;
        const float* Df = (const float*)&Dv[r];
        const float* CDf = (const float*)&Cd[r];
        const float* Sf = (const float*)&Sv[r];
        const float* Gf = (const float*)&Gv[r];
        const float* Cf = (const float*)&Cg[r];
        float gn[4], cn[4];
#pragma unroll
        for (int e = 0; e < 4; ++e) {
            const int w = col + e;
            const bool mL = (w != Wv - 1);     // pad_r zeros last col
            const bool mR = (w != 0);          // pad_l zeros first col
            const float dV = Df[e], cdV = CDf[e], sV = Sf[e];
            const float dL  = mL ? dV  : 0.f;
            const float cdL = mL ? cdV : 0.f;
            const float sL  = mL ? sV  : 0.f;
            const float dR  = mR ? dV  : 0.f;
            const float cdR = mR ? cdV : 0.f;
            const float sR  = mR ? sV  : 0.f;
            const float cgx_ds = sV * sL * sR * cdL * cdR;
            const float height = (cdL * dL + cdR * dR) * frcp(cdL + cdR + EPSF);
            const float gx_ds  = (dR - dL) * 0.5f * frcp(height + EPSF);
            const float a = wpc * Cf[e];
            const float g_ = (a * Gf[e] + cgx_ds * gx_ds) * frcp(a + cgx_ds + EPSF);
            const float c_ = (a + cgx_ds) * inv_wp1;
            gn[e] = vrow ? g_ : 0.f;
            cn[e] = vrow ? c_ : 0.f;
        }
        // left tap: stage-A output at col-1 = lane l-1's elem 3
        float ge = __shfl_up(gn[3], 1, 64);
        float ce = __shfl_up(cn[3], 1, 64);
        ge = l ? ge : 0.f;                     // w = -1 tap is zero
        ce = l ? ce : 0.f;
        const float sw0 = sw_c[3 * r + 0];
        const float sw1 = sw_c[3 * r + 1];
        const float sw2 = sw_c[3 * r + 2];
        float cp;
        // pixel wo0 = 2l : taps w = col-1, col, col+1
        cp = ce    * sp[3 * r + 0].x * sw0; den0 += cp; nom0 = fmaf(cp, ge,    nom0);
        cp = cn[0] * sp[3 * r + 1].x * sw1; den0 += cp; nom0 = fmaf(cp, gn[0], nom0);
        cp = cn[1] * sp[3 * r + 2].x * sw2; den0 += cp; nom0 = fmaf(cp, gn[1], nom0);
        // pixel wo1 = 2l+1 : taps w = col+1, col+2, col+3
        cp = cn[1] * sp[3 * r + 0].y * sw0; den1 += cp; nom1 = fmaf(cp, gn[1], nom1);
        cp = cn[2] * sp[3 * r + 1].y * sw1; den1 += cp; nom1 = fmaf(cp, gn[2], nom1);
        cp = cn[3] * sp[3 * r + 2].y * sw2; den1 += cp; nom1 = fmaf(cp, gn[3], nom1);
    }
    const float gx0 = nom0 * frcp(den0 + EPSF);
    const float cg0 = den0 * inv_sumsw;
    const float gx1 = nom1 * frcp(den1 + EPSF);
    const float cg1 = den1 * inv_sumsw;
    float4 ov = {cg0 * gx0, cg0, cg1 * gx1, cg1};
    *(float4*)(buf + (size_t)z * NPIX + ho * WOv + 2 * l) = ov;
}

// ================= K2: 32->32 channel mix (o split in 2 groups) ===========
__global__ __launch_bounds__(256)
void k2_channel(const float2* __restrict__ buf, const float* __restrict__ ws,
                const float* __restrict__ bias, float* __restrict__ out) {
    const int pg  = blockIdx.x * 256 + threadIdx.x;  // 0..65535
    const int b   = pg >> 14;
    const int pp  = pg & (NPIX - 1);
    const int grp = blockIdx.y;                      // 0..1
    const float* cw_t = ws + 320;
    const float inv_sumcw = ws[1345];

    float nom2[16], den2[16];
#pragma unroll
    for (int i = 0; i < 16; ++i) { nom2[i] = 0.f; den2[i] = 0.f; }

    const int cbase = b * Cv * NPIX + pp;
#pragma unroll
    for (int cc = 0; cc < Cv; ++cc) {
        const float2 v = buf[cbase + cc * NPIX];
#pragma unroll
        for (int oi = 0; oi < 16; ++oi) {
            const float w_ = cw_t[(grp * 16 + oi) * Cv + cc];  // uniform
            nom2[oi] = fmaf(v.x, w_, nom2[oi]);
            den2[oi] = fmaf(v.y, w_, den2[oi]);
        }
    }
#pragma unroll
    for (int oi = 0; oi < 16; ++oi) {
        const int o = grp * 16 + oi;
        const int p = (b * Ov + o) * NPIX + pp;
        const float dn = den2[oi];
        const float g  = nom2[oi] * frcp(dn + EPSF) + bias[o];
        out[p]            = g * 2.0f;
        out[HALF_OUT + p] = dn * inv_sumcw * 0.25f;
    }
}

// ================= fallback: fully fused (round-1) kernel =================
#define TH 4
#define TW 32
#define IH 9
#define IW 65
#define IWP 66
#define NTILE (IH * IW)

__global__ __launch_bounds__(128)
void main_kernel(const float* __restrict__ d,  const float* __restrict__ cd,
                 const float* __restrict__ s,  const float* __restrict__ gx,
                 const float* __restrict__ cgx, const float* __restrict__ sprod,
                 const float* __restrict__ bias, const float* __restrict__ ws,
                 float* __restrict__ out) {
    __shared__ float lgx[IH][IWP];
    __shared__ float lcgx[IH][IWP];
    const int t    = threadIdx.x;
    const int wo_l = t & 31;
    const int ho_l = t >> 5;
    const int wo0  = blockIdx.x * TW;
    const int ho0  = blockIdx.y * TH;
    const int b    = blockIdx.z;
    const int ho   = ho0 + ho_l;
    const int wo   = wo0 + wo_l;
    const float* sw_t = ws + 32;
    const float* cw_t = ws + 320;
    const float inv_sumsw = ws[1344];
    const float inv_sumcw = ws[1345];
    float nom2[Ov], den2[Ov];
#pragma unroll
    for (int o = 0; o < Ov; ++o) { nom2[o] = 0.f; den2[o] = 0.f; }
    const int h_base = 2 * ho0 - 1;
    const int w_base = 2 * wo0 - 1;
    for (int c = 0; c < Cv; ++c) {
        const float wpc = ws[c];
        const float inv_wp1 = frcp(wpc + 1.0f);
        const int ibase = (b * Cv + c) * (Hv * Wv);
        for (int idx = t; idx < NTILE; idx += 128) {
            const int r  = idx / IW;
            const int cc = idx - r * IW;
            const int h  = h_base + r;
            const int w  = w_base + cc;
            float gxn = 0.f, cgxn = 0.f;
            if ((unsigned)h < (unsigned)Hv && (unsigned)w < (unsigned)Wv) {
                const int p = ibase + h * Wv + w;
                const float dv = d[p], cdv = cd[p], sv = s[p];
                const float gxv = gx[p], cgxv = cgx[p];
                const bool mLb = (w != Wv - 1);
                const bool mRb = (w != 0);
                const float dL = mLb ? dv : 0.f, cdL = mLb ? cdv : 0.f, sL = mLb ? sv : 0.f;
                const float dR = mRb ? dv : 0.f, cdR = mRb ? cdv : 0.f, sR = mRb ? sv : 0.f;
                const float cgx_ds = sv * sL * sR * cdL * cdR;
                const float height = (cdL * dL + cdR * dR) * frcp(cdL + cdR + EPSF);
                const float gx_ds  = (dR - dL) * 0.5f * frcp(height + EPSF);
                const float a = wpc * cgxv;
                gxn  = (a * gxv + cgx_ds * gx_ds) * frcp(a + cgx_ds + EPSF);
                cgxn = (a + cgx_ds) * inv_wp1;
            }
            lgx[r][cc]  = gxn;
            lcgx[r][cc] = cgxn;
        }
        __syncthreads();
        const int spb = ((b * Cv + c) * 9 * HOv + ho) * WOv + wo;
        float nom = 0.f, den = 0.f;
#pragma unroll
        for (int k = 0; k < 9; ++k) {
            const int ki = k / 3;
            const int kj = k - ki * 3;
            const float gxr  = lgx[2 * ho_l + ki][2 * wo_l + kj];
            const float cgxr = lcgx[2 * ho_l + ki][2 * wo_l + kj];
            const float spv  = sprod[spb + k * NPIX];
            const float cp   = cgxr * spv * sw_t[c * 9 + k];
            den += cp;
            nom = fmaf(cp, gxr, nom);
        }
        const float gx_sp  = nom * frcp(den + EPSF);
        const float cgx_sp = den * inv_sumsw;
        const float t1 = cgx_sp * gx_sp;
#pragma unroll
        for (int o = 0; o < Ov; ++o) {
            const float w_ = cw_t[o * Cv + c];
            nom2[o] = fmaf(t1, w_, nom2[o]);
            den2[o] = fmaf(cgx_sp, w_, den2[o]);
        }
        __syncthreads();
    }
#pragma unroll
    for (int o = 0; o < Ov; ++o) {
        const int p = ((b * Ov + o) * HOv + ho) * WOv + wo;
        const float dn = den2[o];
        const float g  = nom2[o] * frcp(dn + EPSF) + bias[o];
        out[p]            = g * 2.0f;
        out[HALF_OUT + p] = dn * inv_sumcw * 0.25f;
    }
}

extern "C" void kernel_launch(void* const* d_in, const int* in_sizes, int n_in,
                              void* d_out, int out_size, void* d_ws, size_t ws_size,
                              hipStream_t stream) {
    const float* d_ptr    = (const float*)d_in[0];
    const float* cd_ptr   = (const float*)d_in[1];
    const float* s_ptr    = (const float*)d_in[2];
    // d_in[3] = cs : unused by the reference
    const float* gx_ptr   = (const float*)d_in[4];
    const float* cgx_ptr  = (const float*)d_in[5];
    const float* sp_ptr   = (const float*)d_in[6];
    const float* wp_ptr   = (const float*)d_in[7];
    const float* sw_ptr   = (const float*)d_in[8];
    const float* cw_ptr   = (const float*)d_in[9];
    const float* bias_ptr = (const float*)d_in[10];
    float* out = (float*)d_out;
    float* ws  = (float*)d_ws;

    prep_kernel<<<1, 256, 0, stream>>>(wp_ptr, sw_ptr, cw_ptr, ws);

    if (ws_size >= WS_NEEDED) {
        float2* buf = (float2*)(ws + WS_BUF_OFF);
        dim3 g1(HOv / 4, Bv * Cv, 1);            // 32 x 128 = 4096 blocks
        k1_spatial<<<g1, 256, 0, stream>>>(d_ptr, cd_ptr, s_ptr, gx_ptr, cgx_ptr,
                                           sp_ptr, ws, buf);
        dim3 g2((Bv * NPIX) / 256, 2, 1);        // 256 x 2 blocks
        k2_channel<<<g2, 256, 0, stream>>>(buf, ws, bias_ptr, out);
    } else {
        dim3 grid(WOv / TW, HOv / TH, Bv);
        main_kernel<<<grid, 128, 0, stream>>>(d_ptr, cd_ptr, s_ptr, gx_ptr, cgx_ptr,
                                              sp_ptr, bias_ptr, ws, out);
    }
}